// Round 2
// baseline (77.292 us; speedup 1.0000x reference)
//
#include <hip/hip_runtime.h>

// Problem constants
#define N_ 32
#define T_ 300
#define V_ 25
#define C_ 64      // C_IN
#define F_ 128
#define K_ 3
#define D_ 384     // F_*K_
#define TB 2       // timesteps per block
#define NBLK (N_ * (T_ / TB))   // 4800 blocks

typedef _Float16 f16;
typedef f16  f16x4v __attribute__((ext_vector_type(4)));
typedef f16  f16x8v __attribute__((ext_vector_type(8)));
typedef float f32x4v __attribute__((ext_vector_type(4)));

// workspace byte offsets
#define WS_WT 0         // f16 Wt[384][64]   = 49152 B
#define WS_A2 49152     // f16 A2[3][32][32] =  6144 B
// total ws usage: 55296 B

// ---------------- prep: transpose/convert W, pad/convert A ----------------
__global__ void gcn_prep(const float* __restrict__ A, const float* __restrict__ W,
                         f16* __restrict__ Wt, f16* __restrict__ A2) {
    int tid = blockIdx.x * blockDim.x + threadIdx.x;
    // Wt[d][c] = W[0,0,c,d]
    if (tid < D_ * C_) {
        int d = tid >> 6, c = tid & 63;
        Wt[tid] = (f16)W[c * D_ + d];
    }
    // A2[k][w][v] = A[k][v][w], zero-padded to 32x32
    int t2 = tid - D_ * C_;
    if (t2 >= 0 && t2 < K_ * 32 * 32) {
        int k = t2 >> 10, r = t2 & 1023, w = r >> 5, v = r & 31;
        float val = (w < V_ && v < V_) ? A[(k * V_ + v) * V_ + w] : 0.0f;
        A2[t2] = (f16)val;
    }
}

// ---------------- fused: h = x@W + b (MFMA) -> LDS ; y = A2 @ h (MFMA) ----------------
__global__ __launch_bounds__(256, 2) void gcn_fused(
    const float* __restrict__ x, const f16* __restrict__ Wt,
    const f16* __restrict__ A2g, const float* __restrict__ b,
    float* __restrict__ y)
{
    // x tile: rows tv = t*32+v (v 25..31 zeroed), cols c (stride 72: 16B-aligned rows)
    __shared__ __align__(16) f16 x_lds[64][72];           // 9216 B
    // hT[d][tv], byte-XOR-swizzled: byte = (d*128 + tv*2) ^ ((d&7)<<4)
    __shared__ __align__(16) f16 hT_lds[D_ * 64];         // 49152 B
    __shared__ __align__(16) f16 A2_lds[K_ * 32 * 32];    // 6144 B
    // total 64512 B -> 2 blocks/CU

    const int tid  = threadIdx.x;
    const int lane = tid & 63;
    const int wave = tid >> 6;
    const int l15  = lane & 15;
    const int lgr  = lane >> 4;       // 0..3
    const int koff = lgr * 8;

    const int n  = blockIdx.x / (T_ / TB);
    const int t0 = (blockIdx.x % (T_ / TB)) * TB;

    // ---- stage A2 (6144 B = 384 uint4; block has 256 threads -> 2-step loop) ----
    #pragma unroll
    for (int i = 0; i < 2; ++i) {
        int idx = tid + i * 256;
        if (idx < 384) ((uint4*)A2_lds)[idx] = ((const uint4*)A2g)[idx];
    }

    // ---- stage x tile fp32 -> f16 (800 float4) ----
    {
        const float4* xs = (const float4*)(x + ((size_t)n * T_ + t0) * (V_ * C_));
        #pragma unroll
        for (int i = 0; i < 4; ++i) {
            int idx = tid + i * 256;
            if (idx < TB * V_ * C_ / 4) {
                float4 v4 = xs[idx];
                int e = idx * 4;
                int t = e / (V_ * C_);
                int r = e - t * (V_ * C_);
                int v = r >> 6, c = r & 63;
                f16x4v hv;
                hv[0] = (f16)v4.x; hv[1] = (f16)v4.y; hv[2] = (f16)v4.z; hv[3] = (f16)v4.w;
                *(f16x4v*)&x_lds[t * 32 + v][c] = hv;
            }
        }
    }
    // zero pad rows v in [25,32) for both t (cols 0..63 are the only ones read)
    if (tid < TB * 7 * C_ / 4) {   // 224 threads
        int e = tid * 4;
        int t = e / (7 * C_);
        int r = e - t * (7 * C_);
        int v = 25 + (r >> 6), c = r & 63;
        f16x4v z = {(f16)0.f, (f16)0.f, (f16)0.f, (f16)0.f};
        *(f16x4v*)&x_lds[t * 32 + v][c] = z;
    }

    // per-lane bias values for the hT write: d = wave*96 + mt*16 + lgr*4 + r
    float bb[6][4];
    #pragma unroll
    for (int mt = 0; mt < 6; ++mt)
        #pragma unroll
        for (int r = 0; r < 4; ++r)
            bb[mt][r] = b[wave * 96 + mt * 16 + lgr * 4 + r];

    __syncthreads();

    // ================= step 1: hT[d][tv] = b[d] + sum_c Wt[d][c] * x[tv][c] =================
    // wave owns d range [wave*96, wave*96+96) -> 6 m-tiles of 16
    f16x8v afr[6][2];
    {
        const f16* wb = Wt + (size_t)(wave * 96 + l15) * C_ + koff;
        #pragma unroll
        for (int mt = 0; mt < 6; ++mt) {
            afr[mt][0] = *(const f16x8v*)(wb + mt * 16 * C_);
            afr[mt][1] = *(const f16x8v*)(wb + mt * 16 * C_ + 32);
        }
    }
    f16x8v bfr[4][2];
    #pragma unroll
    for (int nt = 0; nt < 4; ++nt) {
        const f16* xr = &x_lds[nt * 16 + l15][koff];
        bfr[nt][0] = *(const f16x8v*)(xr);
        bfr[nt][1] = *(const f16x8v*)(xr + 32);
    }
    f32x4v zero4 = {0.f, 0.f, 0.f, 0.f};
    f32x4v acc[6][4];
    #pragma unroll
    for (int mt = 0; mt < 6; ++mt)
        #pragma unroll
        for (int nt = 0; nt < 4; ++nt)
            acc[mt][nt] = zero4;
    #pragma unroll
    for (int kt = 0; kt < 2; ++kt)
        #pragma unroll
        for (int mt = 0; mt < 6; ++mt)
            #pragma unroll
            for (int nt = 0; nt < 4; ++nt)
                acc[mt][nt] = __builtin_amdgcn_mfma_f32_16x16x32_f16(
                    afr[mt][kt], bfr[nt][kt], acc[mt][nt], 0, 0, 0);

    // write hT + bias to LDS (f16, swizzled). D frag: row(d) = lgr*4 + r, col(tv) = l15
    {
        char* hb = (char*)hT_lds;
        #pragma unroll
        for (int mt = 0; mt < 6; ++mt) {
            int dbase = wave * 96 + mt * 16 + lgr * 4;
            #pragma unroll
            for (int nt = 0; nt < 4; ++nt) {
                int tv = nt * 16 + l15;
                #pragma unroll
                for (int r = 0; r < 4; ++r) {
                    int d = dbase + r;
                    int off = (d * 128 + tv * 2) ^ ((d & 7) << 4);
                    *(f16*)(hb + off) = (f16)(acc[mt][nt][r] + bb[mt][r]);
                }
            }
        }
    }
    __syncthreads();

    // ================= step 2: y[t][w][f] = sum_{k,v} A2[k][w][v] * hT[k*128+f][t*32+v] =================
    const int t  = wave >> 1;          // 0..1
    const int nh = (wave & 1) * 4;     // f-half: n-tiles nh..nh+3

    f16x8v a2fr[2][3];
    #pragma unroll
    for (int mt = 0; mt < 2; ++mt)
        #pragma unroll
        for (int k = 0; k < K_; ++k)
            a2fr[mt][k] = *(const f16x8v*)&A2_lds[((k * 32) + mt * 16 + l15) * 32 + koff];

    f32x4v acc2[2][4];
    #pragma unroll
    for (int mt = 0; mt < 2; ++mt)
        #pragma unroll
        for (int nt = 0; nt < 4; ++nt)
            acc2[mt][nt] = zero4;

    {
        const char* hb = (const char*)hT_lds;
        #pragma unroll
        for (int nt = 0; nt < 4; ++nt) {
            int f = (nh + nt) * 16 + l15;
            #pragma unroll
            for (int k = 0; k < K_; ++k) {
                int d = k * F_ + f;
                int off = (d * 128 + (t * 32 + koff) * 2) ^ ((d & 7) << 4);
                f16x8v bv = *(const f16x8v*)(hb + off);
                #pragma unroll
                for (int mt = 0; mt < 2; ++mt)
                    acc2[mt][nt] = __builtin_amdgcn_mfma_f32_16x16x32_f16(
                        a2fr[mt][k], bv, acc2[mt][nt], 0, 0, 0);
            }
        }
    }

    // epilogue: y[n][t0+t][w][f] = acc2   (w = mt*16 + lgr*4 + r, f = (nh+nt)*16 + l15)
    {
        float* yr = y + (((size_t)n * T_ + (t0 + t)) * V_) * F_;
        #pragma unroll
        for (int mt = 0; mt < 2; ++mt) {
            int wb = mt * 16 + lgr * 4;
            #pragma unroll
            for (int nt = 0; nt < 4; ++nt) {
                int f = (nh + nt) * 16 + l15;
                #pragma unroll
                for (int r = 0; r < 4; ++r) {
                    int w = wb + r;
                    if (w < V_) {
                        yr[(size_t)w * F_ + f] = acc2[mt][nt][r];
                    }
                }
            }
        }
    }
}

extern "C" void kernel_launch(void* const* d_in, const int* in_sizes, int n_in,
                              void* d_out, int out_size, void* d_ws, size_t ws_size,
                              hipStream_t stream) {
    const float* x = (const float*)d_in[0];
    const float* A = (const float*)d_in[1];
    const float* W = (const float*)d_in[2];
    const float* b = (const float*)d_in[3];
    float* yout = (float*)d_out;

    f16* Wt = (f16*)((char*)d_ws + WS_WT);
    f16* A2 = (f16*)((char*)d_ws + WS_A2);

    const int prep_threads = D_ * C_ + K_ * 32 * 32;  // 27648
    gcn_prep<<<(prep_threads + 255) / 256, 256, 0, stream>>>(A, W, Wt, A2);
    gcn_fused<<<NBLK, 256, 0, stream>>>(x, Wt, A2, b, yout);
}

// Round 3
// 59.341 us; speedup vs baseline: 1.3025x; 1.3025x over previous
//
#include <hip/hip_runtime.h>

// Problem constants
#define N_ 32
#define T_ 300
#define V_ 25
#define C_ 64      // C_IN
#define F_ 128
#define K_ 3
#define D_ 384     // F_*K_
#define TB 2       // timesteps per block
#define NBLK (N_ * (T_ / TB))   // 4800 blocks

typedef _Float16 f16;
typedef f16  f16x4v __attribute__((ext_vector_type(4)));
typedef f16  f16x8v __attribute__((ext_vector_type(8)));
typedef float f32x4v __attribute__((ext_vector_type(4)));

// workspace byte offsets
#define WS_WT 0         // f16 Wt[384][64]   = 49152 B
#define WS_A2 49152     // f16 A2[3][32][32] =  6144 B

// ---------------- prep: transpose/convert W, pad/convert A ----------------
__global__ void gcn_prep(const float* __restrict__ A, const float* __restrict__ W,
                         f16* __restrict__ Wt, f16* __restrict__ A2) {
    int tid = blockIdx.x * blockDim.x + threadIdx.x;
    // Wt[d][c] = W[0,0,c,d]
    if (tid < D_ * C_) {
        int d = tid >> 6, c = tid & 63;
        Wt[tid] = (f16)W[c * D_ + d];
    }
    // A2[k][w][v] = A[k][v][w], zero-padded to 32x32
    int t2 = tid - D_ * C_;
    if (t2 >= 0 && t2 < K_ * 32 * 32) {
        int k = t2 >> 10, r = t2 & 1023, w = r >> 5, v = r & 31;
        float val = (w < V_ && v < V_) ? A[(k * V_ + v) * V_ + w] : 0.0f;
        A2[t2] = (f16)val;
    }
}

// ---------------- fused, k-split double-buffered pipeline ----------------
// step 1 (per k): hT_k[d'][tv] = b[k*128+d'] + sum_c x[tv][c] * Wt[k*128+d'][c]
// step 2 (per k): y[t][w][f] += sum_v A2[k][w][v] * hT_k[f][t*32+v]
__global__ __launch_bounds__(256, 3) void gcn_fused(
    const float* __restrict__ x, const f16* __restrict__ Wt,
    const f16* __restrict__ A2g, const float* __restrict__ b,
    float* __restrict__ y)
{
    // x tile: rows tv = t*32+v (v 25..31 zeroed), cols c (stride 72: 16B-aligned rows)
    __shared__ __align__(16) f16 x_lds[64][72];            // 9216 B
    // hT slices, byte-XOR-swizzled: byte = (d'*128 + tv*2) ^ ((d'&7)<<4)
    __shared__ __align__(16) f16 hT_lds[2][128 * 64];      // 2 x 16384 B
    __shared__ __align__(16) f16 A2_lds[K_ * 32 * 32];     // 6144 B
    // total 48128 B -> 3 blocks/CU

    const int tid  = threadIdx.x;
    const int lane = tid & 63;
    const int wave = tid >> 6;
    const int l15  = lane & 15;
    const int lgr  = lane >> 4;       // 0..3
    const int koff = lgr * 8;

    const int n  = blockIdx.x / (T_ / TB);
    const int t0 = (blockIdx.x % (T_ / TB)) * TB;

    // ---- stage A2 (6144 B = 384 uint4) ----
    #pragma unroll
    for (int i = 0; i < 2; ++i) {
        int idx = tid + i * 256;
        if (idx < 384) ((uint4*)A2_lds)[idx] = ((const uint4*)A2g)[idx];
    }

    // ---- stage x tile fp32 -> f16 (800 float4) ----
    {
        const float4* xs = (const float4*)(x + ((size_t)n * T_ + t0) * (V_ * C_));
        #pragma unroll
        for (int i = 0; i < 4; ++i) {
            int idx = tid + i * 256;
            if (idx < TB * V_ * C_ / 4) {
                float4 v4 = xs[idx];
                int e = idx * 4;
                int t = e / (V_ * C_);
                int r = e - t * (V_ * C_);
                int v = r >> 6, c = r & 63;
                f16x4v hv;
                hv[0] = (f16)v4.x; hv[1] = (f16)v4.y; hv[2] = (f16)v4.z; hv[3] = (f16)v4.w;
                *(f16x4v*)&x_lds[t * 32 + v][c] = hv;
            }
        }
    }
    // zero pad rows v in [25,32) for both t
    if (tid < TB * 7 * C_ / 4) {   // 224 threads
        int e = tid * 4;
        int t = e / (7 * C_);
        int r = e - t * (7 * C_);
        int v = 25 + (r >> 6), c = r & 63;
        f16x4v z = {(f16)0.f, (f16)0.f, (f16)0.f, (f16)0.f};
        *(f16x4v*)&x_lds[t * 32 + v][c] = z;
    }

    // per-lane bias: d = k*128 + wave*32 + nt*16 + l15
    float bias[K_][2];
    #pragma unroll
    for (int k = 0; k < K_; ++k)
        #pragma unroll
        for (int nt = 0; nt < 2; ++nt)
            bias[k][nt] = b[k * F_ + wave * 32 + nt * 16 + l15];

    // Wt B-fragments (rows d = k*128 + wave*32 + nt*16 + l15, cols koff + kt*32)
    const f16* wrow = Wt + (size_t)(wave * 32 + l15) * C_ + koff;
    f16x8v wfrA[2][2], wfrB[2][2];
    #pragma unroll
    for (int nt = 0; nt < 2; ++nt)
        #pragma unroll
        for (int kt = 0; kt < 2; ++kt) {
            wfrA[nt][kt] = *(const f16x8v*)(wrow + (size_t)(0 * F_ + nt * 16) * C_ + kt * 32);
            wfrB[nt][kt] = *(const f16x8v*)(wrow + (size_t)(1 * F_ + nt * 16) * C_ + kt * 32);
        }

    f32x4v zero4 = {0.f, 0.f, 0.f, 0.f};
    f32x4v acc2[2][4];
    #pragma unroll
    for (int mt = 0; mt < 2; ++mt)
        #pragma unroll
        for (int nt = 0; nt < 4; ++nt)
            acc2[mt][nt] = zero4;

    const int t  = wave >> 1;          // step-2 timestep
    const int nh = (wave & 1) * 4;     // step-2 f-half

    __syncthreads();   // x_lds + A2_lds ready

    // ---- GEMM1 for one k: A = x rows (tv), B = Wt cols (d'); D[tv][d'] ----
    auto gemm1 = [&](const f16x8v wfr[2][2], const float bk[2], f16* __restrict__ buf) {
        f16x8v xa[4][2];
        #pragma unroll
        for (int mt = 0; mt < 4; ++mt) {
            const f16* xr = &x_lds[mt * 16 + l15][koff];
            xa[mt][0] = *(const f16x8v*)(xr);
            xa[mt][1] = *(const f16x8v*)(xr + 32);
        }
        f32x4v acc1[4][2];
        #pragma unroll
        for (int mt = 0; mt < 4; ++mt)
            #pragma unroll
            for (int nt = 0; nt < 2; ++nt)
                acc1[mt][nt] = zero4;
        #pragma unroll
        for (int kt = 0; kt < 2; ++kt)
            #pragma unroll
            for (int mt = 0; mt < 4; ++mt)
                #pragma unroll
                for (int nt = 0; nt < 2; ++nt)
                    acc1[mt][nt] = __builtin_amdgcn_mfma_f32_16x16x32_f16(
                        xa[mt][kt], wfr[nt][kt], acc1[mt][nt], 0, 0, 0);
        // write: lane holds D rows tv = mt*16 + lgr*4 + r, col d' = wave*32 + nt*16 + l15
        char* hb = (char*)buf;
        #pragma unroll
        for (int mt = 0; mt < 4; ++mt)
            #pragma unroll
            for (int nt = 0; nt < 2; ++nt) {
                int d = wave * 32 + nt * 16 + l15;
                float bv = bk[nt];
                f16x4v h4;
                #pragma unroll
                for (int r = 0; r < 4; ++r) h4[r] = (f16)(acc1[mt][nt][r] + bv);
                int off = (d * 128 + (mt * 16 + lgr * 4) * 2) ^ ((d & 7) << 4);
                *(f16x4v*)(hb + off) = h4;
            }
    };

    // ---- GEMM2 for one k: A = A2_k (w x v), B = hT_k (v x f); acc2 += ----
    auto gemm2 = [&](int k, const f16* __restrict__ buf) {
        f16x8v a2f[2];
        #pragma unroll
        for (int mt = 0; mt < 2; ++mt)
            a2f[mt] = *(const f16x8v*)&A2_lds[((k * 32) + mt * 16 + l15) * 32 + koff];
        const char* hb = (const char*)buf;
        #pragma unroll
        for (int nt = 0; nt < 4; ++nt) {
            int f = (nh + nt) * 16 + l15;
            int off = (f * 128 + (t * 32 + koff) * 2) ^ ((f & 7) << 4);
            f16x8v bv = *(const f16x8v*)(hb + off);
            #pragma unroll
            for (int mt = 0; mt < 2; ++mt)
                acc2[mt][nt] = __builtin_amdgcn_mfma_f32_16x16x32_f16(
                    a2f[mt], bv, acc2[mt][nt], 0, 0, 0);
        }
    };

    // ---- pipeline: GEMM1(k+1) overlaps GEMM2(k) ----
    gemm1(wfrA, bias[0], hT_lds[0]);
    __syncthreads();

    // prefetch Wt k=2 into wfrA (done with k=0 frags)
    #pragma unroll
    for (int nt = 0; nt < 2; ++nt)
        #pragma unroll
        for (int kt = 0; kt < 2; ++kt)
            wfrA[nt][kt] = *(const f16x8v*)(wrow + (size_t)(2 * F_ + nt * 16) * C_ + kt * 32);

    gemm1(wfrB, bias[1], hT_lds[1]);
    gemm2(0, hT_lds[0]);
    __syncthreads();

    gemm1(wfrA, bias[2], hT_lds[0]);
    gemm2(1, hT_lds[1]);
    __syncthreads();

    gemm2(2, hT_lds[0]);

    // epilogue: y[n][t0+t][w][f] = acc2   (w = mt*16 + lgr*4 + r, f = (nh+nt)*16 + l15)
    {
        float* yr = y + (((size_t)n * T_ + (t0 + t)) * V_) * F_;
        #pragma unroll
        for (int mt = 0; mt < 2; ++mt) {
            int wb = mt * 16 + lgr * 4;
            #pragma unroll
            for (int nt = 0; nt < 4; ++nt) {
                int f = (nh + nt) * 16 + l15;
                #pragma unroll
                for (int r = 0; r < 4; ++r) {
                    int w = wb + r;
                    if (w < V_) {
                        yr[(size_t)w * F_ + f] = acc2[mt][nt][r];
                    }
                }
            }
        }
    }
}

extern "C" void kernel_launch(void* const* d_in, const int* in_sizes, int n_in,
                              void* d_out, int out_size, void* d_ws, size_t ws_size,
                              hipStream_t stream) {
    const float* x = (const float*)d_in[0];
    const float* A = (const float*)d_in[1];
    const float* W = (const float*)d_in[2];
    const float* b = (const float*)d_in[3];
    float* yout = (float*)d_out;

    f16* Wt = (f16*)((char*)d_ws + WS_WT);
    f16* A2 = (f16*)((char*)d_ws + WS_A2);

    const int prep_threads = D_ * C_ + K_ * 32 * 32;  // 27648
    gcn_prep<<<(prep_threads + 255) / 256, 256, 0, stream>>>(A, W, Wt, A2);
    gcn_fused<<<NBLK, 256, 0, stream>>>(x, Wt, A2, b, yout);
}